// Round 5
// baseline (672.316 us; speedup 1.0000x reference)
//
#include <hip/hip_runtime.h>
#include <math.h>

// ---------------- problem dims ----------------
static constexpr int B_   = 64;
static constexpr int H0_  = 480, W0_ = 80;
static constexpr int C0_  = 8, C1_ = 16, C2_ = 16, C3_ = 32;
static constexpr int H1_  = 160, W1_ = 40;
static constexpr int T_   = 40,  WP_ = 20;
static constexpr int IG_  = 640;
static constexpr int HID_ = 256;
static constexpr int G3_  = 768;
static constexpr int OUT_MAIN_ = B_ * T_ * 2 * HID_;

typedef __attribute__((ext_vector_type(8))) short bf16x8;
typedef __attribute__((ext_vector_type(4))) float f32x4;

__device__ inline short f2bf(float f) {
  unsigned u = __builtin_bit_cast(unsigned, f);
  u = (u + 0x7FFFu + ((u >> 16) & 1u)) >> 16;
  return (short)u;
}
__device__ inline float bf2f(short s) {
  return __builtin_bit_cast(float, ((unsigned)(unsigned short)s) << 16);
}
__device__ inline float sigm_(float x) { return 1.f / (1.f + __expf(-x)); }
__device__ inline float tanh_(float x) { return 1.f - 2.f / (1.f + __expf(2.f * x)); }

// split 8 fp32 into bf16 hi + lo such that hi+lo ~= fp32 (fp32-accurate GEMM)
__device__ inline void split8(const float* p, bf16x8* hi, bf16x8* lo) {
  float4 u = *(const float4*)p, v = *(const float4*)(p + 4);
  float f[8] = {u.x, u.y, u.z, u.w, v.x, v.y, v.z, v.w};
  bf16x8 h, l;
#pragma unroll
  for (int i = 0; i < 8; ++i) {
    short hs = f2bf(f[i]);
    h[i] = hs;
    l[i] = f2bf(f[i] - bf2f(hs));
  }
  *hi = h; *lo = l;
}

// ======== fused conv0+relu + conv1+relu + maxpool(3,2), 5 barriers ========
__global__ __launch_bounds__(320) void conv01_pool(
    const float* __restrict__ img, const float* __restrict__ w0,
    const float* __restrict__ b0, const float* __restrict__ w1,
    const float* __restrict__ b1, float* __restrict__ y2) {
  __shared__ float im[28 * 82];
  __shared__ float y0l[4][26 * 82];
  int b = blockIdx.x / 20, r0 = blockIdx.x % 20;
  int tid = threadIdx.x;
  const float* imgb = img + (size_t)b * (H0_ * W0_);

  for (int i = tid; i < 28 * 82; i += 320) {
    int r = i / 82, col = i % 82;
    int gr = r0 * 24 - 2 + r, gc = col - 1;
    float v = 0.f;
    if (gr >= 0 && gr < H0_ && gc >= 0 && gc < W0_) v = imgb[gr * W0_ + gc];
    im[i] = v;
  }
  __syncthreads();

  int oh_l = tid / 40, ow = tid % 40;
  float acc[6][16];
#pragma unroll
  for (int p = 0; p < 6; ++p)
#pragma unroll
    for (int c = 0; c < 16; ++c) acc[p][c] = 0.f;

#pragma unroll 1
  for (int g = 0; g < 2; ++g) {
    if (g) __syncthreads();
#pragma unroll 1
    for (int cl = 0; cl < 4; ++cl) {
      int ci = g * 4 + cl;
      float bci = b0[ci];
      float wr[9];
#pragma unroll
      for (int k = 0; k < 9; ++k) wr[k] = w0[ci * 9 + k];
      for (int i = tid; i < 26 * 82; i += 320) {
        int r = i / 82, col = i % 82;
        int gr = r0 * 24 - 1 + r, gc = col - 1;
        float v = 0.f;
        if (gr >= 0 && gr < H0_ && gc >= 0 && gc < W0_) {
          float s = bci;
#pragma unroll
          for (int kh = 0; kh < 3; ++kh)
#pragma unroll
            for (int kw = 0; kw < 3; ++kw)
              s += im[(r + kh) * 82 + (col - 1 + kw)] * wr[kh * 3 + kw];
          v = fmaxf(s, 0.f);
        }
        y0l[cl][i] = v;
      }
    }
    __syncthreads();
#pragma unroll 1
    for (int cl = 0; cl < 4; ++cl) {
      int ci = g * 4 + cl;
      float rg[5][4];
#pragma unroll
      for (int rr = 0; rr < 5; ++rr) {
        const float2* rp = (const float2*)&y0l[cl][(oh_l * 3 + rr) * 82 + 2 * ow];
        float2 u = rp[0], v = rp[1];
        rg[rr][0] = u.x; rg[rr][1] = u.y; rg[rr][2] = v.x; rg[rr][3] = v.y;
      }
#pragma unroll
      for (int c = 0; c < 16; ++c) {
#pragma unroll
        for (int kh = 0; kh < 3; ++kh)
#pragma unroll
          for (int kw = 0; kw < 3; ++kw) {
            float wv = w1[((c * C0_ + ci) * 3 + kh) * 3 + kw];
#pragma unroll
            for (int ph = 0; ph < 3; ++ph)
#pragma unroll
              for (int pw = 0; pw < 2; ++pw)
                acc[ph * 2 + pw][c] += rg[ph + kh][pw + kw] * wv;
          }
      }
    }
  }
#pragma unroll
  for (int c = 0; c < 16; ++c) {
    float m = acc[0][c];
#pragma unroll
    for (int p = 1; p < 6; ++p) m = fmaxf(m, acc[p][c]);
    y2[(((size_t)b * 16 + c) * 160 + r0 * 8 + oh_l) * 40 + ow] = fmaxf(m + b1[c], 0.f);
  }
}

// ======== conv2 (16->16) + relu ========
__global__ __launch_bounds__(320) void conv2_relu(
    const float* __restrict__ y2, const float* __restrict__ w2,
    const float* __restrict__ b2, float* __restrict__ y3) {
  __shared__ float t2[16 * 18 * 42];
  int b = blockIdx.x / 10, r0 = blockIdx.x % 10;
  int tid = threadIdx.x;
  const float* yb = y2 + (size_t)b * (16 * 160 * 40);
  for (int i = tid; i < 16 * 18 * 42; i += 320) {
    int col = i % 42; int r = (i / 42) % 18; int ci = i / (42 * 18);
    int gr = r0 * 16 - 1 + r, gc = col - 1;
    float v = 0.f;
    if (gr >= 0 && gr < 160 && gc >= 0 && gc < 40) v = yb[(ci * 160 + gr) * 40 + gc];
    t2[i] = v;
  }
  __syncthreads();
#pragma unroll 1
  for (int p = tid; p < 640; p += 320) {
    int oh = p / 40, ow = p % 40;
    float acc[16];
#pragma unroll
    for (int c = 0; c < 16; ++c) acc[c] = 0.f;
#pragma unroll 1
    for (int ci = 0; ci < 16; ++ci) {
      float pt[9];
#pragma unroll
      for (int kh = 0; kh < 3; ++kh)
#pragma unroll
        for (int kw = 0; kw < 3; ++kw)
          pt[kh * 3 + kw] = t2[(ci * 18 + oh + kh) * 42 + ow + kw];
#pragma unroll
      for (int c = 0; c < 16; ++c)
#pragma unroll
        for (int k = 0; k < 9; ++k)
          acc[c] += pt[k] * w2[(c * 16 + ci) * 9 + k];
    }
#pragma unroll
    for (int c = 0; c < 16; ++c)
      y3[(((size_t)b * 16 + c) * 160 + r0 * 16 + oh) * 40 + ow] = fmaxf(acc[c] + b2[c], 0.f);
  }
}

// ======== conv3 + relu + maxpool(4,2), writes x[t][b][wo][c] fp32 ========
__global__ __launch_bounds__(320) void conv3_pool(
    const float* __restrict__ y3, const float* __restrict__ w3,
    const float* __restrict__ b3, float* __restrict__ x) {
  __shared__ float t3[16 * 10 * 42];
  __shared__ float w3t[144 * 32];
  int b = blockIdx.x / 20, tp = blockIdx.x % 20;
  int tid = threadIdx.x;
  const float* yb = y3 + (size_t)b * (16 * 160 * 40);
  for (int i = tid; i < 16 * 10 * 42; i += 320) {
    int col = i % 42; int r = (i / 42) % 10; int ci = i / 420;
    int gr = tp * 8 - 1 + r, gc = col - 1;
    float v = 0.f;
    if (gr >= 0 && gr < 160 && gc >= 0 && gc < 40) v = yb[(ci * 160 + gr) * 40 + gc];
    t3[i] = v;
  }
  for (int i = tid; i < 144 * 32; i += 320) {
    int k = i / 32, c = i % 32;
    w3t[i] = w3[c * 144 + k];
  }
  __syncthreads();
#pragma unroll 1
  for (int it = 0; it < 4; ++it) {
    int wk = it * 320 + tid;
    int c = wk & 31;
    int wo = (wk >> 5) % 20;
    int t2 = wk / 640;
    int t = tp * 2 + t2;
    float acc[8];
#pragma unroll
    for (int p = 0; p < 8; ++p) acc[p] = 0.f;
#pragma unroll 1
    for (int ci = 0; ci < 16; ++ci) {
      float rg[6][4];
#pragma unroll
      for (int rr = 0; rr < 6; ++rr) {
        const float2* rp = (const float2*)&t3[(ci * 10 + 4 * t2 + rr) * 42 + 2 * wo];
        float2 u = rp[0], v = rp[1];
        rg[rr][0] = u.x; rg[rr][1] = u.y; rg[rr][2] = v.x; rg[rr][3] = v.y;
      }
#pragma unroll
      for (int kh = 0; kh < 3; ++kh)
#pragma unroll
        for (int kw = 0; kw < 3; ++kw) {
          float wv = w3t[((ci * 3 + kh) * 3 + kw) * 32 + c];
#pragma unroll
          for (int ph = 0; ph < 4; ++ph)
#pragma unroll
            for (int pw = 0; pw < 2; ++pw)
              acc[ph * 2 + pw] += rg[ph + kh][pw + kw] * wv;
        }
    }
    float m = acc[0];
#pragma unroll
    for (int p = 1; p < 8; ++p) m = fmaxf(m, acc[p]);
    x[(((size_t)t * 64 + b) * 20 + wo) * 32 + c] = fmaxf(m + b3[c], 0.f);
  }
}

// ======== gx GEMM, fp32-accurate via 3-term bf16 split MFMA ========
// grid (20, 6, 2): 128x128 tiles, M=2560 N=768 K=640. 256 thr = 4 waves.
// Staging: wave = k-subchunk (8 elems), lane = row -> conflict-free b128 writes.
__global__ __launch_bounds__(256) void gemm_gx_mfma(
    const float* __restrict__ x, const float* __restrict__ wih_f,
    const float* __restrict__ wih_b, const float* __restrict__ bih_f,
    const float* __restrict__ bih_b, float* __restrict__ gx) {
  __shared__ __align__(16) short Ah[4 * 128 * 8], Al[4 * 128 * 8];
  __shared__ __align__(16) short Bh[4 * 128 * 8], Bl[4 * 128 * 8];
  int bm = blockIdx.x * 128, bn = blockIdx.y * 128, dir = blockIdx.z;
  const float* W = dir ? wih_b : wih_f;
  const float* bias = dir ? bih_b : bih_f;
  float* C = gx + (size_t)dir * (T_ * B_) * G3_;
  int tid = threadIdx.x;
  int wave = tid >> 6, lane = tid & 63, q = lane >> 4, n = lane & 15;
  int wm = (wave & 1) * 64, wn2 = (wave >> 1) * 64;
  f32x4 acc[4][4];
#pragma unroll
  for (int mi = 0; mi < 4; ++mi)
#pragma unroll
    for (int ni = 0; ni < 4; ++ni) acc[mi][ni] = (f32x4){0.f, 0.f, 0.f, 0.f};

  for (int k0 = 0; k0 < IG_; k0 += 32) {
    // stage: wave=qc plane, lane=row (rows lane, lane+64)
    bf16x8 h, l;
    split8(x + (size_t)(bm + lane) * IG_ + k0 + wave * 8, &h, &l);
    *(bf16x8*)&Ah[(wave * 128 + lane) * 8] = h;
    *(bf16x8*)&Al[(wave * 128 + lane) * 8] = l;
    split8(x + (size_t)(bm + lane + 64) * IG_ + k0 + wave * 8, &h, &l);
    *(bf16x8*)&Ah[(wave * 128 + lane + 64) * 8] = h;
    *(bf16x8*)&Al[(wave * 128 + lane + 64) * 8] = l;
    split8(W + (size_t)(bn + lane) * IG_ + k0 + wave * 8, &h, &l);
    *(bf16x8*)&Bh[(wave * 128 + lane) * 8] = h;
    *(bf16x8*)&Bl[(wave * 128 + lane) * 8] = l;
    split8(W + (size_t)(bn + lane + 64) * IG_ + k0 + wave * 8, &h, &l);
    *(bf16x8*)&Bh[(wave * 128 + lane + 64) * 8] = h;
    *(bf16x8*)&Bl[(wave * 128 + lane + 64) * 8] = l;
    __syncthreads();
    bf16x8 ah[4], al[4], bh[4], bl[4];
#pragma unroll
    for (int mi = 0; mi < 4; ++mi) {
      ah[mi] = *(const bf16x8*)&Ah[(q * 128 + wm + mi * 16 + n) * 8];
      al[mi] = *(const bf16x8*)&Al[(q * 128 + wm + mi * 16 + n) * 8];
    }
#pragma unroll
    for (int ni = 0; ni < 4; ++ni) {
      bh[ni] = *(const bf16x8*)&Bh[(q * 128 + wn2 + ni * 16 + n) * 8];
      bl[ni] = *(const bf16x8*)&Bl[(q * 128 + wn2 + ni * 16 + n) * 8];
    }
#pragma unroll
    for (int mi = 0; mi < 4; ++mi)
#pragma unroll
      for (int ni = 0; ni < 4; ++ni) {
        acc[mi][ni] = __builtin_amdgcn_mfma_f32_16x16x32_bf16(
            al[mi], bh[ni], acc[mi][ni], 0, 0, 0);
        acc[mi][ni] = __builtin_amdgcn_mfma_f32_16x16x32_bf16(
            ah[mi], bl[ni], acc[mi][ni], 0, 0, 0);
        acc[mi][ni] = __builtin_amdgcn_mfma_f32_16x16x32_bf16(
            ah[mi], bh[ni], acc[mi][ni], 0, 0, 0);
      }
    __syncthreads();
  }
#pragma unroll
  for (int mi = 0; mi < 4; ++mi)
#pragma unroll
    for (int ni = 0; ni < 4; ++ni)
#pragma unroll
      for (int r = 0; r < 4; ++r) {
        int row = bm + wm + mi * 16 + q * 4 + r;
        int col = bn + wn2 + ni * 16 + n;
        C[(size_t)row * G3_ + col] = acc[mi][ni][r] + bias[col];
      }
}

// ======== weight-stationary MFMA GRU, identity-mapped LDS ========
__global__ __launch_bounds__(1024) void gru_mfma(
    const float* __restrict__ gx,
    const float* __restrict__ whh_f, const float* __restrict__ whh_b,
    const float* __restrict__ bhh_f, const float* __restrict__ bhh_b,
    const float* __restrict__ h0, float* __restrict__ out) {
  __shared__ __align__(16) short wn[32 * 256 * 8];    // 128 KB [ch][j][8]
  __shared__ __align__(16) short hb[2][32 * 16 * 8];  // 2x8 KB [ch][b][8]
  int blk = blockIdx.x, dir = blk >> 2, mb = blk & 3;
  const float* Wh  = dir ? whh_b : whh_f;
  const float* bhh = dir ? bhh_b : bhh_f;
  int tid = threadIdx.x;
  int wave = tid >> 6, lane = tid & 63, q = lane >> 4, n = lane & 15;
  int jw = wave << 4;

  for (int idx = tid; idx < 256 * 32; idx += 1024) {
    int j = idx >> 5, ch = idx & 31;
    const float* src = Wh + (size_t)(512 + j) * HID_ + ch * 8;
    float4 u = *(const float4*)src, v = *(const float4*)(src + 4);
    short* d = &wn[(ch * 256 + j) * 8];
    d[0] = f2bf(u.x); d[1] = f2bf(u.y); d[2] = f2bf(u.z); d[3] = f2bf(u.w);
    d[4] = f2bf(v.x); d[5] = f2bf(v.y); d[6] = f2bf(v.z); d[7] = f2bf(v.w);
  }
  if (tid < 512) {
    int b = tid >> 5, ch = tid & 31;
    const float* src = h0 + (size_t)(dir * 64 + mb * 16 + b) * HID_ + ch * 8;
    float4 u = *(const float4*)src, v = *(const float4*)(src + 4);
    short* d = &hb[0][(ch * 16 + b) * 8];
    d[0] = f2bf(u.x); d[1] = f2bf(u.y); d[2] = f2bf(u.z); d[3] = f2bf(u.w);
    d[4] = f2bf(v.x); d[5] = f2bf(v.y); d[6] = f2bf(v.z); d[7] = f2bf(v.w);
  }
  bf16x8 Br[8], Bz[8];
#pragma unroll
  for (int kt = 0; kt < 8; ++kt) {
    const float* pr = Wh + (size_t)(jw + n) * HID_ + kt * 32 + q * 8;
    const float* pz = Wh + (size_t)(256 + jw + n) * HID_ + kt * 32 + q * 8;
    float4 u = *(const float4*)pr, v = *(const float4*)(pr + 4);
    Br[kt] = (bf16x8){f2bf(u.x), f2bf(u.y), f2bf(u.z), f2bf(u.w),
                      f2bf(v.x), f2bf(v.y), f2bf(v.z), f2bf(v.w)};
    float4 uz = *(const float4*)pz, vz = *(const float4*)(pz + 4);
    Bz[kt] = (bf16x8){f2bf(uz.x), f2bf(uz.y), f2bf(uz.z), f2bf(uz.w),
                      f2bf(vz.x), f2bf(vz.y), f2bf(vz.z), f2bf(vz.w)};
  }
  float hold[4];
#pragma unroll
  for (int r = 0; r < 4; ++r)
    hold[r] = h0[(size_t)(dir * 64 + mb * 16 + q * 4 + r) * HID_ + jw + n];
  float bh0 = bhh[jw + n], bh1 = bhh[256 + jw + n], bh2 = bhh[512 + jw + n];
  int chc = (jw + n) >> 3, ce = (jw + n) & 7;
  __syncthreads();

  for (int s = 0; s < T_; ++s) {
    int t = dir ? (T_ - 1 - s) : s;
    const short* hc = hb[s & 1];
    short* hx = hb[(s & 1) ^ 1];
    const float* gxt = gx + ((size_t)(dir * T_ + t) * B_ + mb * 16) * G3_;
    float xr[4], xz[4], xn[4];
#pragma unroll
    for (int r = 0; r < 4; ++r) {
      const float* gxb = gxt + (size_t)(q * 4 + r) * G3_ + jw + n;
      xr[r] = gxb[0]; xz[r] = gxb[256]; xn[r] = gxb[512];
    }
    f32x4 a0 = {0.f, 0.f, 0.f, 0.f}, a1 = a0, a2 = a0;
#pragma unroll
    for (int kt = 0; kt < 8; ++kt) {
      bf16x8 af = *(const bf16x8*)&hc[((kt * 4 + q) * 16 + n) * 8];
      bf16x8 bn = *(const bf16x8*)&wn[((kt * 4 + q) * 256 + jw + n) * 8];
      a0 = __builtin_amdgcn_mfma_f32_16x16x32_bf16(af, Br[kt], a0, 0, 0, 0);
      a1 = __builtin_amdgcn_mfma_f32_16x16x32_bf16(af, Bz[kt], a1, 0, 0, 0);
      a2 = __builtin_amdgcn_mfma_f32_16x16x32_bf16(af, bn, a2, 0, 0, 0);
    }
#pragma unroll
    for (int r = 0; r < 4; ++r) {
      float rg = sigm_(xr[r] + a0[r] + bh0);
      float zg = sigm_(xz[r] + a1[r] + bh1);
      float ng = tanh_(xn[r] + rg * (a2[r] + bh2));
      float hnew = (1.f - zg) * ng + zg * hold[r];
      hold[r] = hnew;
      int gb = mb * 16 + q * 4 + r;
      out[((size_t)gb * T_ + t) * (2 * HID_) + dir * HID_ + jw + n] = hnew;
      hx[(chc * 16 + q * 4 + r) * 8 + ce] = f2bf(hnew);
    }
    __syncthreads();
  }
#pragma unroll
  for (int r = 0; r < 4; ++r)
    out[(size_t)OUT_MAIN_ + (size_t)(dir * 64 + mb * 16 + q * 4 + r) * HID_ + jw + n] = hold[r];
}

// ---------------- launch ----------------
extern "C" void kernel_launch(void* const* d_in, const int* in_sizes, int n_in,
                              void* d_out, int out_size, void* d_ws, size_t ws_size,
                              hipStream_t stream) {
  (void)in_sizes; (void)n_in; (void)out_size; (void)ws_size;
  const float* img    = (const float*)d_in[0];
  const float* hid0   = (const float*)d_in[1];
  const float* c0w    = (const float*)d_in[2];
  const float* c0b    = (const float*)d_in[3];
  const float* c1w    = (const float*)d_in[4];
  const float* c1b    = (const float*)d_in[5];
  const float* c2w    = (const float*)d_in[6];
  const float* c2b    = (const float*)d_in[7];
  const float* c3w    = (const float*)d_in[8];
  const float* c3b    = (const float*)d_in[9];
  const float* wih_f  = (const float*)d_in[10];
  const float* whh_f  = (const float*)d_in[11];
  const float* bih_f  = (const float*)d_in[12];
  const float* bhh_f  = (const float*)d_in[13];
  const float* wih_b  = (const float*)d_in[14];
  const float* whh_b  = (const float*)d_in[15];
  const float* bih_b  = (const float*)d_in[16];
  const float* bhh_b  = (const float*)d_in[17];
  float* out = (float*)d_out;

  // ws layout (float offsets): y2 6.55M | y3 6.55M | x 1.64M | gx 3.93M
  float* wsf = (float*)d_ws;
  float* y2  = wsf;
  float* y3  = wsf + 6553600;
  float* x   = wsf + 13107200;
  float* gx  = wsf + 14745600;

  conv01_pool<<<64 * 20, 320, 0, stream>>>(img, c0w, c0b, c1w, c1b, y2);
  conv2_relu<<<64 * 10, 320, 0, stream>>>(y2, c2w, c2b, y3);
  conv3_pool<<<64 * 20, 320, 0, stream>>>(y3, c3w, c3b, x);
  gemm_gx_mfma<<<dim3(20, 6, 2), 256, 0, stream>>>(x, wih_f, wih_b, bih_f, bih_b, gx);
  gru_mfma<<<8, 1024, 0, stream>>>(gx, whh_f, whh_b, bhh_f, bhh_b, hid0, out);
}

// Round 6
// 649.049 us; speedup vs baseline: 1.0358x; 1.0358x over previous
//
#include <hip/hip_runtime.h>
#include <math.h>

// ---------------- problem dims ----------------
static constexpr int B_   = 64;
static constexpr int H0_  = 480, W0_ = 80;
static constexpr int C0_  = 8, C1_ = 16, C2_ = 16, C3_ = 32;
static constexpr int H1_  = 160, W1_ = 40;
static constexpr int T_   = 40,  WP_ = 20;
static constexpr int IG_  = 640;
static constexpr int HID_ = 256;
static constexpr int G3_  = 768;
static constexpr int OUT_MAIN_ = B_ * T_ * 2 * HID_;

typedef __attribute__((ext_vector_type(8))) short bf16x8;
typedef __attribute__((ext_vector_type(4))) float f32x4;

__device__ inline short f2bf(float f) {
  unsigned u = __builtin_bit_cast(unsigned, f);
  u = (u + 0x7FFFu + ((u >> 16) & 1u)) >> 16;
  return (short)u;
}
__device__ inline float bf2f(short s) {
  return __builtin_bit_cast(float, ((unsigned)(unsigned short)s) << 16);
}
__device__ inline float sigm_(float x) { return 1.f / (1.f + __expf(-x)); }
__device__ inline float tanh_(float x) { return 1.f - 2.f / (1.f + __expf(2.f * x)); }

__device__ inline void split8(const float* p, bf16x8* hi, bf16x8* lo) {
  float4 u = *(const float4*)p, v = *(const float4*)(p + 4);
  float f[8] = {u.x, u.y, u.z, u.w, v.x, v.y, v.z, v.w};
  bf16x8 h, l;
#pragma unroll
  for (int i = 0; i < 8; ++i) {
    short hs = f2bf(f[i]);
    h[i] = hs;
    l[i] = f2bf(f[i] - bf2f(hs));
  }
  *hi = h; *lo = l;
}

// ======== conv0+conv1+pool, register-resident ========
// Block (b, r0): 8 pooled rows x 40 cols x 16 ch. Thread = (oh_l, ow).
// img tile in LDS (28x84, 9.4 KB); per-thread 7x6 img patch in registers,
// y0 recomputed per ci in registers; main loop has no LDS traffic/barriers.
__global__ __launch_bounds__(320) void conv01_pool(
    const float* __restrict__ img, const float* __restrict__ w0,
    const float* __restrict__ b0, const float* __restrict__ w1,
    const float* __restrict__ b1, float* __restrict__ y2) {
  __shared__ float im[28 * 84];   // rows r0*24-2..+25, cols -2..81
  int b = blockIdx.x / 20, r0 = blockIdx.x % 20;
  int tid = threadIdx.x;
  const float* imgb = img + (size_t)b * (H0_ * W0_);
  for (int i = tid; i < 28 * 84; i += 320) {
    int r = i / 84, col = i % 84;
    int gr = r0 * 24 - 2 + r, gc = col - 2;
    float v = 0.f;
    if (gr >= 0 && gr < H0_ && gc >= 0 && gc < W0_) v = imgb[gr * W0_ + gc];
    im[i] = v;
  }
  __syncthreads();

  int oh_l = tid / 40, ow = tid % 40;
  float P[7][6];
#pragma unroll
  for (int r = 0; r < 7; ++r) {
    const float* rp = &im[(3 * oh_l + r) * 84 + 2 * ow];
#pragma unroll
    for (int c = 0; c < 6; ++c) P[r][c] = rp[c];
  }
  bool rowOK[5], colOK[4];
#pragma unroll
  for (int rr = 0; rr < 5; ++rr) {
    int ry = r0 * 24 - 1 + 3 * oh_l + rr;
    rowOK[rr] = (ry >= 0 && ry < H0_);
  }
#pragma unroll
  for (int cc = 0; cc < 4; ++cc) {
    int cy = 2 * ow - 1 + cc;
    colOK[cc] = (cy >= 0 && cy < W0_);
  }
  float acc[6][16];
#pragma unroll
  for (int p = 0; p < 6; ++p)
#pragma unroll
    for (int c = 0; c < 16; ++c) acc[p][c] = 0.f;

#pragma unroll 1
  for (int ci = 0; ci < C0_; ++ci) {
    float wr[9];
#pragma unroll
    for (int k = 0; k < 9; ++k) wr[k] = w0[ci * 9 + k];
    float bci = b0[ci];
    float y0[5][4];
#pragma unroll
    for (int rr = 0; rr < 5; ++rr)
#pragma unroll
      for (int cc = 0; cc < 4; ++cc) {
        float s = bci;
#pragma unroll
        for (int kh = 0; kh < 3; ++kh)
#pragma unroll
          for (int kw = 0; kw < 3; ++kw)
            s += P[rr + kh][cc + kw] * wr[kh * 3 + kw];
        y0[rr][cc] = (rowOK[rr] && colOK[cc]) ? fmaxf(s, 0.f) : 0.f;
      }
#pragma unroll
    for (int c = 0; c < 16; ++c)
#pragma unroll
      for (int kh = 0; kh < 3; ++kh)
#pragma unroll
        for (int kw = 0; kw < 3; ++kw) {
          float wv = w1[((c * C0_ + ci) * 3 + kh) * 3 + kw];  // uniform s_load
#pragma unroll
          for (int ph = 0; ph < 3; ++ph)
#pragma unroll
            for (int pw = 0; pw < 2; ++pw)
              acc[ph * 2 + pw][c] += y0[ph + kh][pw + kw] * wv;
        }
  }
#pragma unroll
  for (int c = 0; c < 16; ++c) {
    float m = acc[0][c];
#pragma unroll
    for (int p = 1; p < 6; ++p) m = fmaxf(m, acc[p][c]);
    y2[(((size_t)b * 16 + c) * 160 + r0 * 8 + oh_l) * 40 + ow] = fmaxf(m + b1[c], 0.f);
  }
}

// ======== conv2 (16->16) + relu ========
__global__ __launch_bounds__(320) void conv2_relu(
    const float* __restrict__ y2, const float* __restrict__ w2,
    const float* __restrict__ b2, float* __restrict__ y3) {
  __shared__ float t2[16 * 18 * 42];
  int b = blockIdx.x / 10, r0 = blockIdx.x % 10;
  int tid = threadIdx.x;
  const float* yb = y2 + (size_t)b * (16 * 160 * 40);
  for (int i = tid; i < 16 * 18 * 42; i += 320) {
    int col = i % 42; int r = (i / 42) % 18; int ci = i / (42 * 18);
    int gr = r0 * 16 - 1 + r, gc = col - 1;
    float v = 0.f;
    if (gr >= 0 && gr < 160 && gc >= 0 && gc < 40) v = yb[(ci * 160 + gr) * 40 + gc];
    t2[i] = v;
  }
  __syncthreads();
#pragma unroll 1
  for (int p = tid; p < 640; p += 320) {
    int oh = p / 40, ow = p % 40;
    float acc[16];
#pragma unroll
    for (int c = 0; c < 16; ++c) acc[c] = 0.f;
#pragma unroll 1
    for (int ci = 0; ci < 16; ++ci) {
      float pt[9];
#pragma unroll
      for (int kh = 0; kh < 3; ++kh)
#pragma unroll
        for (int kw = 0; kw < 3; ++kw)
          pt[kh * 3 + kw] = t2[(ci * 18 + oh + kh) * 42 + ow + kw];
#pragma unroll
      for (int c = 0; c < 16; ++c)
#pragma unroll
        for (int k = 0; k < 9; ++k)
          acc[c] += pt[k] * w2[(c * 16 + ci) * 9 + k];
    }
#pragma unroll
    for (int c = 0; c < 16; ++c)
      y3[(((size_t)b * 16 + c) * 160 + r0 * 16 + oh) * 40 + ow] = fmaxf(acc[c] + b2[c], 0.f);
  }
}

// ======== conv3 + relu + maxpool(4,2), writes x[t][b][wo][c] fp32 ========
__global__ __launch_bounds__(320) void conv3_pool(
    const float* __restrict__ y3, const float* __restrict__ w3,
    const float* __restrict__ b3, float* __restrict__ x) {
  __shared__ float t3[16 * 10 * 42];
  __shared__ float w3t[144 * 32];
  int b = blockIdx.x / 20, tp = blockIdx.x % 20;
  int tid = threadIdx.x;
  const float* yb = y3 + (size_t)b * (16 * 160 * 40);
  for (int i = tid; i < 16 * 10 * 42; i += 320) {
    int col = i % 42; int r = (i / 42) % 10; int ci = i / 420;
    int gr = tp * 8 - 1 + r, gc = col - 1;
    float v = 0.f;
    if (gr >= 0 && gr < 160 && gc >= 0 && gc < 40) v = yb[(ci * 160 + gr) * 40 + gc];
    t3[i] = v;
  }
  for (int i = tid; i < 144 * 32; i += 320) {
    int k = i / 32, c = i % 32;
    w3t[i] = w3[c * 144 + k];
  }
  __syncthreads();
#pragma unroll 1
  for (int it = 0; it < 4; ++it) {
    int wk = it * 320 + tid;
    int c = wk & 31;
    int wo = (wk >> 5) % 20;
    int t2 = wk / 640;
    int t = tp * 2 + t2;
    float acc[8];
#pragma unroll
    for (int p = 0; p < 8; ++p) acc[p] = 0.f;
#pragma unroll 1
    for (int ci = 0; ci < 16; ++ci) {
      float rg[6][4];
#pragma unroll
      for (int rr = 0; rr < 6; ++rr) {
        const float2* rp = (const float2*)&t3[(ci * 10 + 4 * t2 + rr) * 42 + 2 * wo];
        float2 u = rp[0], v = rp[1];
        rg[rr][0] = u.x; rg[rr][1] = u.y; rg[rr][2] = v.x; rg[rr][3] = v.y;
      }
#pragma unroll
      for (int kh = 0; kh < 3; ++kh)
#pragma unroll
        for (int kw = 0; kw < 3; ++kw) {
          float wv = w3t[((ci * 3 + kh) * 3 + kw) * 32 + c];
#pragma unroll
          for (int ph = 0; ph < 4; ++ph)
#pragma unroll
            for (int pw = 0; pw < 2; ++pw)
              acc[ph * 2 + pw] += rg[ph + kh][pw + kw] * wv;
        }
    }
    float m = acc[0];
#pragma unroll
    for (int p = 1; p < 8; ++p) m = fmaxf(m, acc[p]);
    x[(((size_t)t * 64 + b) * 20 + wo) * 32 + c] = fmaxf(m + b3[c], 0.f);
  }
}

// ======== gx GEMM, fp32-accurate via 3-term bf16 split MFMA ========
__global__ __launch_bounds__(256) void gemm_gx_mfma(
    const float* __restrict__ x, const float* __restrict__ wih_f,
    const float* __restrict__ wih_b, const float* __restrict__ bih_f,
    const float* __restrict__ bih_b, float* __restrict__ gx) {
  __shared__ __align__(16) short Ah[4 * 128 * 8], Al[4 * 128 * 8];
  __shared__ __align__(16) short Bh[4 * 128 * 8], Bl[4 * 128 * 8];
  int bm = blockIdx.x * 128, bn = blockIdx.y * 128, dir = blockIdx.z;
  const float* W = dir ? wih_b : wih_f;
  const float* bias = dir ? bih_b : bih_f;
  float* C = gx + (size_t)dir * (T_ * B_) * G3_;
  int tid = threadIdx.x;
  int wave = tid >> 6, lane = tid & 63, q = lane >> 4, n = lane & 15;
  int wm = (wave & 1) * 64, wn2 = (wave >> 1) * 64;
  f32x4 acc[4][4];
#pragma unroll
  for (int mi = 0; mi < 4; ++mi)
#pragma unroll
    for (int ni = 0; ni < 4; ++ni) acc[mi][ni] = (f32x4){0.f, 0.f, 0.f, 0.f};

  for (int k0 = 0; k0 < IG_; k0 += 32) {
    bf16x8 h, l;
    split8(x + (size_t)(bm + lane) * IG_ + k0 + wave * 8, &h, &l);
    *(bf16x8*)&Ah[(wave * 128 + lane) * 8] = h;
    *(bf16x8*)&Al[(wave * 128 + lane) * 8] = l;
    split8(x + (size_t)(bm + lane + 64) * IG_ + k0 + wave * 8, &h, &l);
    *(bf16x8*)&Ah[(wave * 128 + lane + 64) * 8] = h;
    *(bf16x8*)&Al[(wave * 128 + lane + 64) * 8] = l;
    split8(W + (size_t)(bn + lane) * IG_ + k0 + wave * 8, &h, &l);
    *(bf16x8*)&Bh[(wave * 128 + lane) * 8] = h;
    *(bf16x8*)&Bl[(wave * 128 + lane) * 8] = l;
    split8(W + (size_t)(bn + lane + 64) * IG_ + k0 + wave * 8, &h, &l);
    *(bf16x8*)&Bh[(wave * 128 + lane + 64) * 8] = h;
    *(bf16x8*)&Bl[(wave * 128 + lane + 64) * 8] = l;
    __syncthreads();
    bf16x8 ah[4], al[4], bh[4], bl[4];
#pragma unroll
    for (int mi = 0; mi < 4; ++mi) {
      ah[mi] = *(const bf16x8*)&Ah[(q * 128 + wm + mi * 16 + n) * 8];
      al[mi] = *(const bf16x8*)&Al[(q * 128 + wm + mi * 16 + n) * 8];
    }
#pragma unroll
    for (int ni = 0; ni < 4; ++ni) {
      bh[ni] = *(const bf16x8*)&Bh[(q * 128 + wn2 + ni * 16 + n) * 8];
      bl[ni] = *(const bf16x8*)&Bl[(q * 128 + wn2 + ni * 16 + n) * 8];
    }
#pragma unroll
    for (int mi = 0; mi < 4; ++mi)
#pragma unroll
      for (int ni = 0; ni < 4; ++ni) {
        acc[mi][ni] = __builtin_amdgcn_mfma_f32_16x16x32_bf16(
            al[mi], bh[ni], acc[mi][ni], 0, 0, 0);
        acc[mi][ni] = __builtin_amdgcn_mfma_f32_16x16x32_bf16(
            ah[mi], bl[ni], acc[mi][ni], 0, 0, 0);
        acc[mi][ni] = __builtin_amdgcn_mfma_f32_16x16x32_bf16(
            ah[mi], bh[ni], acc[mi][ni], 0, 0, 0);
      }
    __syncthreads();
  }
#pragma unroll
  for (int mi = 0; mi < 4; ++mi)
#pragma unroll
    for (int ni = 0; ni < 4; ++ni)
#pragma unroll
      for (int r = 0; r < 4; ++r) {
        int row = bm + wm + mi * 16 + q * 4 + r;
        int col = bn + wn2 + ni * 16 + n;
        C[(size_t)row * G3_ + col] = acc[mi][ni][r] + bias[col];
      }
}

// ======== weight-stationary MFMA GRU, identity-mapped LDS ========
__global__ __launch_bounds__(1024) void gru_mfma(
    const float* __restrict__ gx,
    const float* __restrict__ whh_f, const float* __restrict__ whh_b,
    const float* __restrict__ bhh_f, const float* __restrict__ bhh_b,
    const float* __restrict__ h0, float* __restrict__ out) {
  __shared__ __align__(16) short wn[32 * 256 * 8];    // 128 KB [ch][j][8]
  __shared__ __align__(16) short hb[2][32 * 16 * 8];  // 2x8 KB [ch][b][8]
  int blk = blockIdx.x, dir = blk >> 2, mb = blk & 3;
  const float* Wh  = dir ? whh_b : whh_f;
  const float* bhh = dir ? bhh_b : bhh_f;
  int tid = threadIdx.x;
  int wave = tid >> 6, lane = tid & 63, q = lane >> 4, n = lane & 15;
  int jw = wave << 4;

  for (int idx = tid; idx < 256 * 32; idx += 1024) {
    int j = idx >> 5, ch = idx & 31;
    const float* src = Wh + (size_t)(512 + j) * HID_ + ch * 8;
    float4 u = *(const float4*)src, v = *(const float4*)(src + 4);
    short* d = &wn[(ch * 256 + j) * 8];
    d[0] = f2bf(u.x); d[1] = f2bf(u.y); d[2] = f2bf(u.z); d[3] = f2bf(u.w);
    d[4] = f2bf(v.x); d[5] = f2bf(v.y); d[6] = f2bf(v.z); d[7] = f2bf(v.w);
  }
  if (tid < 512) {
    int b = tid >> 5, ch = tid & 31;
    const float* src = h0 + (size_t)(dir * 64 + mb * 16 + b) * HID_ + ch * 8;
    float4 u = *(const float4*)src, v = *(const float4*)(src + 4);
    short* d = &hb[0][(ch * 16 + b) * 8];
    d[0] = f2bf(u.x); d[1] = f2bf(u.y); d[2] = f2bf(u.z); d[3] = f2bf(u.w);
    d[4] = f2bf(v.x); d[5] = f2bf(v.y); d[6] = f2bf(v.z); d[7] = f2bf(v.w);
  }
  bf16x8 Br[8], Bz[8];
#pragma unroll
  for (int kt = 0; kt < 8; ++kt) {
    const float* pr = Wh + (size_t)(jw + n) * HID_ + kt * 32 + q * 8;
    const float* pz = Wh + (size_t)(256 + jw + n) * HID_ + kt * 32 + q * 8;
    float4 u = *(const float4*)pr, v = *(const float4*)(pr + 4);
    Br[kt] = (bf16x8){f2bf(u.x), f2bf(u.y), f2bf(u.z), f2bf(u.w),
                      f2bf(v.x), f2bf(v.y), f2bf(v.z), f2bf(v.w)};
    float4 uz = *(const float4*)pz, vz = *(const float4*)(pz + 4);
    Bz[kt] = (bf16x8){f2bf(uz.x), f2bf(uz.y), f2bf(uz.z), f2bf(uz.w),
                      f2bf(vz.x), f2bf(vz.y), f2bf(vz.z), f2bf(vz.w)};
  }
  float hold[4];
#pragma unroll
  for (int r = 0; r < 4; ++r)
    hold[r] = h0[(size_t)(dir * 64 + mb * 16 + q * 4 + r) * HID_ + jw + n];
  float bh0 = bhh[jw + n], bh1 = bhh[256 + jw + n], bh2 = bhh[512 + jw + n];
  int chc = (jw + n) >> 3, ce = (jw + n) & 7;
  __syncthreads();

  for (int s = 0; s < T_; ++s) {
    int t = dir ? (T_ - 1 - s) : s;
    const short* hc = hb[s & 1];
    short* hx = hb[(s & 1) ^ 1];
    const float* gxt = gx + ((size_t)(dir * T_ + t) * B_ + mb * 16) * G3_;
    float xr[4], xz[4], xn[4];
#pragma unroll
    for (int r = 0; r < 4; ++r) {
      const float* gxb = gxt + (size_t)(q * 4 + r) * G3_ + jw + n;
      xr[r] = gxb[0]; xz[r] = gxb[256]; xn[r] = gxb[512];
    }
    f32x4 a0 = {0.f, 0.f, 0.f, 0.f}, a1 = a0, a2 = a0;
#pragma unroll
    for (int kt = 0; kt < 8; ++kt) {
      bf16x8 af = *(const bf16x8*)&hc[((kt * 4 + q) * 16 + n) * 8];
      bf16x8 bn = *(const bf16x8*)&wn[((kt * 4 + q) * 256 + jw + n) * 8];
      a0 = __builtin_amdgcn_mfma_f32_16x16x32_bf16(af, Br[kt], a0, 0, 0, 0);
      a1 = __builtin_amdgcn_mfma_f32_16x16x32_bf16(af, Bz[kt], a1, 0, 0, 0);
      a2 = __builtin_amdgcn_mfma_f32_16x16x32_bf16(af, bn, a2, 0, 0, 0);
    }
#pragma unroll
    for (int r = 0; r < 4; ++r) {
      float rg = sigm_(xr[r] + a0[r] + bh0);
      float zg = sigm_(xz[r] + a1[r] + bh1);
      float ng = tanh_(xn[r] + rg * (a2[r] + bh2));
      float hnew = (1.f - zg) * ng + zg * hold[r];
      hold[r] = hnew;
      int gb = mb * 16 + q * 4 + r;
      out[((size_t)gb * T_ + t) * (2 * HID_) + dir * HID_ + jw + n] = hnew;
      hx[(chc * 16 + q * 4 + r) * 8 + ce] = f2bf(hnew);
    }
    __syncthreads();
  }
#pragma unroll
  for (int r = 0; r < 4; ++r)
    out[(size_t)OUT_MAIN_ + (size_t)(dir * 64 + mb * 16 + q * 4 + r) * HID_ + jw + n] = hold[r];
}

// ---------------- launch ----------------
extern "C" void kernel_launch(void* const* d_in, const int* in_sizes, int n_in,
                              void* d_out, int out_size, void* d_ws, size_t ws_size,
                              hipStream_t stream) {
  (void)in_sizes; (void)n_in; (void)out_size; (void)ws_size;
  const float* img    = (const float*)d_in[0];
  const float* hid0   = (const float*)d_in[1];
  const float* c0w    = (const float*)d_in[2];
  const float* c0b    = (const float*)d_in[3];
  const float* c1w    = (const float*)d_in[4];
  const float* c1b    = (const float*)d_in[5];
  const float* c2w    = (const float*)d_in[6];
  const float* c2b    = (const float*)d_in[7];
  const float* c3w    = (const float*)d_in[8];
  const float* c3b    = (const float*)d_in[9];
  const float* wih_f  = (const float*)d_in[10];
  const float* whh_f  = (const float*)d_in[11];
  const float* bih_f  = (const float*)d_in[12];
  const float* bhh_f  = (const float*)d_in[13];
  const float* wih_b  = (const float*)d_in[14];
  const float* whh_b  = (const float*)d_in[15];
  const float* bih_b  = (const float*)d_in[16];
  const float* bhh_b  = (const float*)d_in[17];
  float* out = (float*)d_out;

  float* wsf = (float*)d_ws;
  float* y2  = wsf;
  float* y3  = wsf + 6553600;
  float* x   = wsf + 13107200;
  float* gx  = wsf + 14745600;

  conv01_pool<<<64 * 20, 320, 0, stream>>>(img, c0w, c0b, c1w, c1b, y2);
  conv2_relu<<<64 * 10, 320, 0, stream>>>(y2, c2w, c2b, y3);
  conv3_pool<<<64 * 20, 320, 0, stream>>>(y3, c3w, c3b, x);
  gemm_gx_mfma<<<dim3(20, 6, 2), 256, 0, stream>>>(x, wih_f, wih_b, bih_f, bih_b, gx);
  gru_mfma<<<8, 1024, 0, stream>>>(gx, whh_f, whh_b, bhh_f, bhh_b, hid0, out);
}